// Round 2
// baseline (419.729 us; speedup 1.0000x reference)
//
#include <hip/hip_runtime.h>
#include <hip/hip_bf16.h>
#include <stdint.h>

typedef short bf16x8 __attribute__((ext_vector_type(8)));
typedef float f32x4  __attribute__((ext_vector_type(4)));

#define MFMA_BF16(a,b,c) __builtin_amdgcn_mfma_f32_16x16x32_bf16((a),(b),(c),0,0,0)

// async global->LDS, 16B per lane. lds ptr must be wave-uniform; lane i lands at l + i*16.
__device__ __forceinline__ void async_ld16(const void* g, void* l) {
  __builtin_amdgcn_global_load_lds(
      (const __attribute__((address_space(1))) void*)g,
      (__attribute__((address_space(3))) void*)l, 16, 0, 0);
}

__device__ __forceinline__ unsigned short bf16_bits(float x) {
  __hip_bfloat16 h = __float2bfloat16(x);
  return *(unsigned short*)&h;
}

// f32 -> bf16, 4 elems/thread, n divisible by 4.
__global__ void __launch_bounds__(256)
cvt_f32_bf16(const float* __restrict__ in, __hip_bfloat16* __restrict__ out, int n)
{
  const int i = (blockIdx.x * 256 + threadIdx.x) * 4;
  if (i >= n) return;
  const float4 v = *(const float4*)(in + i);
  ushort4 u;
  u.x = bf16_bits(v.x); u.y = bf16_bits(v.y);
  u.z = bf16_bits(v.z); u.w = bf16_bits(v.w);
  *(ushort4*)((unsigned short*)out + i) = u;
}

// C[M,N] = A[M,K] * B[N,K]^T, bf16 in, f32 accumulate. 128x128 tile, BK=32,
// 256 threads = 4 waves in 2x2, each wave 64x64 (4x4 of 16x16x32 mfma).
// EPI==0: scatter epilogue for QKV (o0=q [B,H,S,64], o1=k [B,H,S,64], o2=vT [B,H,64,S]), bf16
// EPI==1: plain row-major *f32* store to of with ldc = gridDim.x*128
template<int EPI>
__global__ void __launch_bounds__(256)
gemm_bt(const __hip_bfloat16* __restrict__ A,
        const __hip_bfloat16* __restrict__ B,
        int K,
        __hip_bfloat16* __restrict__ o0,
        __hip_bfloat16* __restrict__ o1,
        __hip_bfloat16* __restrict__ o2,
        float* __restrict__ of)
{
  __shared__ __align__(16) __hip_bfloat16 As[128 * 32];
  __shared__ __align__(16) __hip_bfloat16 Bs[128 * 32];

  const int tid  = threadIdx.x;
  const int w    = tid >> 6;
  const int lane = tid & 63;
  const int quad = lane >> 4;
  const int l15  = lane & 15;

  const int m0 = blockIdx.y * 128;
  const int n0 = blockIdx.x * 128;

  // staging: lane i of wave w covers row w*16 + i/4, 16B chunk i%4 of the 64B (32-elem) row
  const int srow = w * 16 + (lane >> 2);
  const int skc  = (lane & 3) * 8;

  const __hip_bfloat16* Ag0 = A + (size_t)(m0 + srow)      * K + skc;
  const __hip_bfloat16* Ag1 = A + (size_t)(m0 + 64 + srow) * K + skc;
  const __hip_bfloat16* Bg0 = B + (size_t)(n0 + srow)      * K + skc;
  const __hip_bfloat16* Bg1 = B + (size_t)(n0 + 64 + srow) * K + skc;

  __hip_bfloat16* asd0 = As + w * 512;
  __hip_bfloat16* asd1 = As + 2048 + w * 512;
  __hip_bfloat16* bsd0 = Bs + w * 512;
  __hip_bfloat16* bsd1 = Bs + 2048 + w * 512;

  const int wm = (w >> 1) * 64;
  const int wn = (w & 1) * 64;

  f32x4 acc[4][4] = {};

  for (int k0 = 0; k0 < K; k0 += 32) {
    __syncthreads();
    async_ld16(Ag0 + k0, asd0);
    async_ld16(Ag1 + k0, asd1);
    async_ld16(Bg0 + k0, bsd0);
    async_ld16(Bg1 + k0, bsd1);
    __syncthreads();            // drains vmcnt(0): LDS-DMA complete for all waves

    bf16x8 af[4], bfr[4];
#pragma unroll
    for (int t = 0; t < 4; ++t) {
      af[t]  = *(const bf16x8*)(As + (wm + t * 16 + l15) * 32 + quad * 8);
      bfr[t] = *(const bf16x8*)(Bs + (wn + t * 16 + l15) * 32 + quad * 8);
    }
#pragma unroll
    for (int mt = 0; mt < 4; ++mt)
#pragma unroll
      for (int nt = 0; nt < 4; ++nt)
        acc[mt][nt] = MFMA_BF16(af[mt], bfr[nt], acc[mt][nt]);
  }

  const int ldc = (int)gridDim.x * 128;
#pragma unroll
  for (int mt = 0; mt < 4; ++mt) {
#pragma unroll
    for (int nt = 0; nt < 4; ++nt) {
#pragma unroll
      for (int r = 0; r < 4; ++r) {
        // verified C layout: col = lane&15, row = (lane>>4)*4 + reg
        const int m = m0 + wm + mt * 16 + quad * 4 + r;
        const int n = n0 + wn + nt * 16 + l15;
        if (EPI == 0) {
          const __hip_bfloat16 hv = __float2bfloat16(acc[mt][nt][r]);
          const int b = m >> 11, s = m & 2047;
          const int which = n >> 10, rem = n & 1023;
          const int h = rem >> 6, d = rem & 63;
          const int bh = b * 16 + h;
          if (which == 0)      o0[((size_t)(bh * 2048 + s) << 6) + d] = hv;
          else if (which == 1) o1[((size_t)(bh * 2048 + s) << 6) + d] = hv;
          else                 o2[((size_t)(bh * 64 + d) << 11) + s] = hv;
        } else {
          of[(size_t)m * ldc + n] = acc[mt][nt][r];
        }
      }
    }
  }
}

// RMSNorm (over DH=64) + RoPE, in place on q and k buffers laid out [B,H,S,64] bf16.
// One wave per row. q additionally pre-scaled by DH^-0.5 = 0.125 (exact).
__global__ void __launch_bounds__(256)
norm_rope(__hip_bfloat16* __restrict__ qb,
          __hip_bfloat16* __restrict__ kb,
          const float* __restrict__ freqs,
          const float* __restrict__ qw,
          const float* __restrict__ kw)
{
  const int wid  = blockIdx.x * 4 + (threadIdx.x >> 6);
  const int lane = threadIdx.x & 63;
  const int which = wid >> 16;          // 65536 rows per tensor
  const int idx   = wid & 65535;        // bh*2048 + s
  const int s     = idx & 2047;

  __hip_bfloat16* buf = which ? kb : qb;
  const float* wgt = which ? kw : qw;

  const size_t base = (size_t)idx * 64;
  float x = __bfloat162float(buf[base + lane]);
  float ss = x * x;
#pragma unroll
  for (int off = 1; off < 64; off <<= 1) ss += __shfl_xor(ss, off);
  const float scale = rsqrtf(ss * (1.0f / 64.0f) + 1e-6f);
  const float y = x * scale * wgt[lane];

  const float f = freqs[s * 64 + (lane & 31)];
  const float c = cosf(f), sn = sinf(f);
  const float part = __shfl_xor(y, 32);
  float o = (lane < 32) ? (y * c - part * sn) : (y * c + part * sn);
  if (which == 0) o *= 0.125f;          // fold attention scale into q (exact pow2)
  buf[base + lane] = __float2bfloat16(o);
}

// Flash attention, causal. q,k: [B,H,S,64] bf16 (q pre-scaled); vT: [B,H,64,S] bf16.
// Grid (S/64, B*H), 256 threads = 4 waves; wave handles 16 q rows; key tiles of 32.
__global__ void __launch_bounds__(256)
attn(const __hip_bfloat16* __restrict__ q,
     const __hip_bfloat16* __restrict__ k,
     const __hip_bfloat16* __restrict__ vt,
     __hip_bfloat16* __restrict__ ao)
{
  __shared__ __align__(16) __hip_bfloat16 P[4][16 * 56];  // stride 56: 16B-aligned b128, 2-way banks

  const int w    = threadIdx.x >> 6;
  const int lane = threadIdx.x & 63;
  const int quad = lane >> 4;
  const int l15  = lane & 15;

  const int bh = blockIdx.y;
  const int b  = bh >> 4, h = bh & 15;
  const int q0 = blockIdx.x * 64 + w * 16;

  const __hip_bfloat16* qb = q  + (size_t)bh * 2048 * 64;
  const __hip_bfloat16* kb = k  + (size_t)bh * 2048 * 64;
  const __hip_bfloat16* vb = vt + (size_t)bh * 64 * 2048;

  // Q A-operand frags: lane holds A[m=l15][kd = quad*8 + j], two K-steps of 32
  bf16x8 aq0 = *(const bf16x8*)(qb + (size_t)(q0 + l15) * 64 + quad * 8);
  bf16x8 aq1 = *(const bf16x8*)(qb + (size_t)(q0 + l15) * 64 + 32 + quad * 8);

  f32x4 o[4] = {};
  float mrow[4] = {-1e30f, -1e30f, -1e30f, -1e30f};
  float lrow[4] = {0.f, 0.f, 0.f, 0.f};

  const int ntile = ((q0 + 15) >> 5) + 1;   // last tile t0 <= q0, so no fully-masked row
  for (int kt = 0; kt < ntile; ++kt) {
    const int t0 = kt * 32;

    const __hip_bfloat16* kp0 = kb + (size_t)(t0 + l15) * 64 + quad * 8;
    const __hip_bfloat16* kp1 = kb + (size_t)(t0 + 16 + l15) * 64 + quad * 8;
    bf16x8 b00 = *(const bf16x8*)(kp0);
    bf16x8 b01 = *(const bf16x8*)(kp0 + 32);
    bf16x8 b10 = *(const bf16x8*)(kp1);
    bf16x8 b11 = *(const bf16x8*)(kp1 + 32);

    f32x4 c0 = {}, c1 = {};
    c0 = MFMA_BF16(aq0, b00, c0);
    c0 = MFMA_BF16(aq1, b01, c0);
    c1 = MFMA_BF16(aq0, b10, c1);
    c1 = MFMA_BF16(aq1, b11, c1);

    __builtin_amdgcn_wave_barrier();
#pragma unroll
    for (int r = 0; r < 4; ++r) {
      const int qr = q0 + quad * 4 + r;           // C layout: row = quad*4+reg
      float s0 = c0[r];                            // scale folded into q
      float s1 = c1[r];
      if (t0 + l15 > qr)      s0 = -1e30f;         // causal mask (col = l15)
      if (t0 + 16 + l15 > qr) s1 = -1e30f;

      float mx = fmaxf(s0, s1);
      mx = fmaxf(mx, __shfl_xor(mx, 1));
      mx = fmaxf(mx, __shfl_xor(mx, 2));
      mx = fmaxf(mx, __shfl_xor(mx, 4));
      mx = fmaxf(mx, __shfl_xor(mx, 8));

      const float mnew  = fmaxf(mrow[r], mx);
      const float alpha = __expf(mrow[r] - mnew);
      const float p0 = __expf(s0 - mnew);
      const float p1 = __expf(s1 - mnew);
      float rs = p0 + p1;
      rs += __shfl_xor(rs, 1);
      rs += __shfl_xor(rs, 2);
      rs += __shfl_xor(rs, 4);
      rs += __shfl_xor(rs, 8);

      lrow[r] = lrow[r] * alpha + rs;
      mrow[r] = mnew;
      o[0][r] *= alpha; o[1][r] *= alpha; o[2][r] *= alpha; o[3][r] *= alpha;

      P[w][(quad * 4 + r) * 56 + l15]      = __float2bfloat16(p0);
      P[w][(quad * 4 + r) * 56 + 16 + l15] = __float2bfloat16(p1);
    }
    __builtin_amdgcn_wave_barrier();

    // P as A-operand: lane holds P[m=l15][t = quad*8 + j]  (same-wave LDS RAW: DS in-order)
    bf16x8 pf = *(const bf16x8*)(&P[w][l15 * 56 + quad * 8]);
#pragma unroll
    for (int dt = 0; dt < 4; ++dt) {
      bf16x8 vf = *(const bf16x8*)(vb + (size_t)(dt * 16 + l15) * 2048 + t0 + quad * 8);
      o[dt] = MFMA_BF16(pf, vf, o[dt]);
    }
  }

#pragma unroll
  for (int r = 0; r < 4; ++r) {
    const float inv = 1.0f / lrow[r];
    const int qv = q0 + quad * 4 + r;
    const size_t row = ((size_t)(b * 2048 + qv)) * 1024 + h * 64;
#pragma unroll
    for (int dt = 0; dt < 4; ++dt)
      ao[row + dt * 16 + l15] = __float2bfloat16(o[dt][r] * inv);
  }
}

extern "C" void kernel_launch(void* const* d_in, const int* in_sizes, int n_in,
                              void* d_out, int out_size, void* d_ws, size_t ws_size,
                              hipStream_t stream)
{
  const float* x    = (const float*)d_in[0];
  // d_in[1] = mask: exactly causal -1e9; applied analytically in attn.
  const float* rf   = (const float*)d_in[2];
  const float* wqkv = (const float*)d_in[3];
  const float* wout = (const float*)d_in[4];
  const float* qw   = (const float*)d_in[5];
  const float* kw   = (const float*)d_in[6];

  const size_t NE = (size_t)2 * 16 * 2048 * 64;   // 4,194,304 elems per [B,H,S,64] tensor
  const int NX    = 2 * 2048 * 1024;              // 4,194,304
  const int NWQKV = 3072 * 1024;                  // 3,145,728
  const int NWOUT = 1024 * 1024;                  // 1,048,576

  __hip_bfloat16* qb  = (__hip_bfloat16*)d_ws;
  __hip_bfloat16* kb  = qb  + NE;
  __hip_bfloat16* vt  = kb  + NE;
  __hip_bfloat16* ao  = vt  + NE;
  __hip_bfloat16* xb  = ao  + NE;
  __hip_bfloat16* wqb = xb  + NX;
  __hip_bfloat16* wob = wqb + NWQKV;
  // total: (4*NE + NX + NWQKV + NWOUT) * 2 B  ~= 48.2 MB

  // f32 -> bf16 conversions
  cvt_f32_bf16<<<NX / 1024,    256, 0, stream>>>(x,    xb,  NX);
  cvt_f32_bf16<<<NWQKV / 1024, 256, 0, stream>>>(wqkv, wqb, NWQKV);
  cvt_f32_bf16<<<NWOUT / 1024, 256, 0, stream>>>(wout, wob, NWOUT);

  // QKV: C[4096,3072] = xb[4096,1024] @ wqb[3072,1024]^T, scatter to q/k/vT
  gemm_bt<0><<<dim3(24, 32), 256, 0, stream>>>(xb, wqb, 1024, qb, kb, vt, nullptr);
  // RMSNorm + RoPE on q,k (131072 rows, 4 waves/block)
  norm_rope<<<32768, 256, 0, stream>>>(qb, kb, rf, qw, kw);
  // causal flash attention -> ao[4096,1024] bf16
  attn<<<dim3(32, 32), 256, 0, stream>>>(qb, kb, vt, ao);
  // out = ao @ wob[1024,1024]^T -> d_out (f32)
  gemm_bt<1><<<dim3(8, 32), 256, 0, stream>>>(ao, wob, 1024,
                                              nullptr, nullptr, nullptr, (float*)d_out);
}

// Round 3
// 416.746 us; speedup vs baseline: 1.0072x; 1.0072x over previous
//
#include <hip/hip_runtime.h>
#include <hip/hip_bf16.h>
#include <stdint.h>

typedef short bf16x8 __attribute__((ext_vector_type(8)));
typedef float f32x4  __attribute__((ext_vector_type(4)));

#define MFMA_BF16(a,b,c) __builtin_amdgcn_mfma_f32_16x16x32_bf16((a),(b),(c),0,0,0)

// async global->LDS, 16B per lane. lds ptr must be wave-uniform; lane i lands at l + i*16.
__device__ __forceinline__ void async_ld16(const void* g, void* l) {
  __builtin_amdgcn_global_load_lds(
      (const __attribute__((address_space(1))) void*)g,
      (__attribute__((address_space(3))) void*)l, 16, 0, 0);
}

__device__ __forceinline__ unsigned short bf16_bits(float x) {
  __hip_bfloat16 h = __float2bfloat16(x);
  return *(unsigned short*)&h;
}

// f32 -> bf16, 4 elems/thread, n divisible by 4.
__global__ void __launch_bounds__(256)
cvt_f32_bf16(const float* __restrict__ in, __hip_bfloat16* __restrict__ out, int n)
{
  const int i = (blockIdx.x * 256 + threadIdx.x) * 4;
  if (i >= n) return;
  const float4 v = *(const float4*)(in + i);
  ushort4 u;
  u.x = bf16_bits(v.x); u.y = bf16_bits(v.y);
  u.z = bf16_bits(v.z); u.w = bf16_bits(v.w);
  *(ushort4*)((unsigned short*)out + i) = u;
}

// C[M,N] = A[M,K] * B[N,K]^T, bf16 in, f32 accumulate. 128x128 tile, BK=32,
// 256 threads = 4 waves in 2x2, each wave 64x64 (4x4 of 16x16x32 mfma).
// EPI==0: scatter epilogue for QKV (o0=q [B,H,S,64], o1=k [B,H,S,64], o2=vT [B,H,64,S]), bf16
// EPI==1: plain row-major *f32* store to of with ldc = gridDim.x*128
template<int EPI>
__global__ void __launch_bounds__(256)
gemm_bt(const __hip_bfloat16* __restrict__ A,
        const __hip_bfloat16* __restrict__ B,
        int K,
        __hip_bfloat16* __restrict__ o0,
        __hip_bfloat16* __restrict__ o1,
        __hip_bfloat16* __restrict__ o2,
        float* __restrict__ of)
{
  __shared__ __align__(16) __hip_bfloat16 As[128 * 32];
  __shared__ __align__(16) __hip_bfloat16 Bs[128 * 32];

  const int tid  = threadIdx.x;
  const int w    = tid >> 6;
  const int lane = tid & 63;
  const int quad = lane >> 4;
  const int l15  = lane & 15;

  const int m0 = blockIdx.y * 128;
  const int n0 = blockIdx.x * 128;

  const int srow = w * 16 + (lane >> 2);
  const int skc  = (lane & 3) * 8;

  const __hip_bfloat16* Ag0 = A + (size_t)(m0 + srow)      * K + skc;
  const __hip_bfloat16* Ag1 = A + (size_t)(m0 + 64 + srow) * K + skc;
  const __hip_bfloat16* Bg0 = B + (size_t)(n0 + srow)      * K + skc;
  const __hip_bfloat16* Bg1 = B + (size_t)(n0 + 64 + srow) * K + skc;

  __hip_bfloat16* asd0 = As + w * 512;
  __hip_bfloat16* asd1 = As + 2048 + w * 512;
  __hip_bfloat16* bsd0 = Bs + w * 512;
  __hip_bfloat16* bsd1 = Bs + 2048 + w * 512;

  const int wm = (w >> 1) * 64;
  const int wn = (w & 1) * 64;

  f32x4 acc[4][4] = {};

  for (int k0 = 0; k0 < K; k0 += 32) {
    __syncthreads();
    async_ld16(Ag0 + k0, asd0);
    async_ld16(Ag1 + k0, asd1);
    async_ld16(Bg0 + k0, bsd0);
    async_ld16(Bg1 + k0, bsd1);
    __syncthreads();            // drains vmcnt(0): LDS-DMA complete for all waves

    bf16x8 af[4], bfr[4];
#pragma unroll
    for (int t = 0; t < 4; ++t) {
      af[t]  = *(const bf16x8*)(As + (wm + t * 16 + l15) * 32 + quad * 8);
      bfr[t] = *(const bf16x8*)(Bs + (wn + t * 16 + l15) * 32 + quad * 8);
    }
#pragma unroll
    for (int mt = 0; mt < 4; ++mt)
#pragma unroll
      for (int nt = 0; nt < 4; ++nt)
        acc[mt][nt] = MFMA_BF16(af[mt], bfr[nt], acc[mt][nt]);
  }

  const int ldc = (int)gridDim.x * 128;
#pragma unroll
  for (int mt = 0; mt < 4; ++mt) {
#pragma unroll
    for (int nt = 0; nt < 4; ++nt) {
#pragma unroll
      for (int r = 0; r < 4; ++r) {
        // verified C layout: col = lane&15, row = (lane>>4)*4 + reg
        const int m = m0 + wm + mt * 16 + quad * 4 + r;
        const int n = n0 + wn + nt * 16 + l15;
        if (EPI == 0) {
          const __hip_bfloat16 hv = __float2bfloat16(acc[mt][nt][r]);
          const int b = m >> 11, s = m & 2047;
          const int which = n >> 10, rem = n & 1023;
          const int h = rem >> 6, d = rem & 63;
          const int bh = b * 16 + h;
          if (which == 0)      o0[((size_t)(bh * 2048 + s) << 6) + d] = hv;
          else if (which == 1) o1[((size_t)(bh * 2048 + s) << 6) + d] = hv;
          else                 o2[((size_t)(bh * 64 + d) << 11) + s] = hv;
        } else {
          of[(size_t)m * ldc + n] = acc[mt][nt][r];
        }
      }
    }
  }
}

// RMSNorm (over DH=64) + RoPE, in place on q and k buffers laid out [B,H,S,64] bf16.
// One wave per row. q additionally pre-scaled by DH^-0.5 = 0.125 (exact).
__global__ void __launch_bounds__(256)
norm_rope(__hip_bfloat16* __restrict__ qb,
          __hip_bfloat16* __restrict__ kb,
          const float* __restrict__ freqs,
          const float* __restrict__ qw,
          const float* __restrict__ kw)
{
  const int wid  = blockIdx.x * 4 + (threadIdx.x >> 6);
  const int lane = threadIdx.x & 63;
  const int which = wid >> 16;          // 65536 rows per tensor
  const int idx   = wid & 65535;        // bh*2048 + s
  const int s     = idx & 2047;

  __hip_bfloat16* buf = which ? kb : qb;
  const float* wgt = which ? kw : qw;

  const size_t base = (size_t)idx * 64;
  float x = __bfloat162float(buf[base + lane]);
  float ss = x * x;
#pragma unroll
  for (int off = 1; off < 64; off <<= 1) ss += __shfl_xor(ss, off);
  const float scale = rsqrtf(ss * (1.0f / 64.0f) + 1e-6f);
  const float y = x * scale * wgt[lane];

  const float f = freqs[s * 64 + (lane & 31)];
  const float c = cosf(f), sn = sinf(f);
  const float part = __shfl_xor(y, 32);
  float o = (lane < 32) ? (y * c - part * sn) : (y * c + part * sn);
  if (which == 0) o *= 0.125f;          // fold attention scale into q (exact pow2)
  buf[base + lane] = __float2bfloat16(o);
}

// Flash attention, causal, S^T formulation (no LDS, no P round-trip).
// q,k: [B,H,S,64] bf16 (q pre-scaled); vT: [B,H,64,S] bf16. ao: [B,S,H*64] bf16.
// Grid (S/64, B*H), 256 threads = 4 waves; wave handles 16 q rows (q = q0 + l15);
// key tiles of 32, K rows loaded in permuted order so S^T C-rows land where the
// PV B-operand (P[q=l15][t=quad*8+j]) needs them: perm(l15) = (l15>>2)*8 + (l15&3).
__global__ void __launch_bounds__(256)
attn(const __hip_bfloat16* __restrict__ q,
     const __hip_bfloat16* __restrict__ k,
     const __hip_bfloat16* __restrict__ vt,
     __hip_bfloat16* __restrict__ ao)
{
  const int w    = threadIdx.x >> 6;
  const int lane = threadIdx.x & 63;
  const int quad = lane >> 4;
  const int l15  = lane & 15;

  const int bh = blockIdx.y;
  const int b  = bh >> 4, h = bh & 15;
  // reversed dispatch: heavy q-tiles (long key loops) launch first -> better tail packing
  const int qt = (int)gridDim.x - 1 - (int)blockIdx.x;
  const int q0 = qt * 64 + w * 16;
  const int qi = q0 + l15;              // this lane's query row

  const __hip_bfloat16* qb = q  + (size_t)bh * 2048 * 64;
  const __hip_bfloat16* kb = k  + (size_t)bh * 2048 * 64;
  const __hip_bfloat16* vb = vt + (size_t)bh * 64 * 2048;

  // Q = B-operand: lane holds Q[n=q0+l15][k=quad*8+j], two K=32 steps over d
  const bf16x8 bq0 = *(const bf16x8*)(qb + (size_t)qi * 64 + quad * 8);
  const bf16x8 bq1 = *(const bf16x8*)(qb + (size_t)qi * 64 + 32 + quad * 8);

  const int pr = ((l15 >> 2) * 8) + (l15 & 3);   // permuted key row for c0; c1 uses pr+4

  f32x4 o[4] = {};
  float mcur = -1e30f, lcur = 0.f;

  const int ntile = ((q0 + 15) >> 5) + 1;

  // fragment loaders (plain per-lane loads -> prefetchable)
  bf16x8 ka[4], va[4], kn[4], vn[4];
  {
    const __hip_bfloat16* kr0 = kb + (size_t)pr * 64;
    const __hip_bfloat16* kr1 = kb + (size_t)(pr + 4) * 64;
    ka[0] = *(const bf16x8*)(kr0 + quad * 8);
    ka[1] = *(const bf16x8*)(kr0 + 32 + quad * 8);
    ka[2] = *(const bf16x8*)(kr1 + quad * 8);
    ka[3] = *(const bf16x8*)(kr1 + 32 + quad * 8);
#pragma unroll
    for (int dt = 0; dt < 4; ++dt)
      va[dt] = *(const bf16x8*)(vb + (size_t)(dt * 16 + l15) * 2048 + quad * 8);
  }

  for (int kt = 0; kt < ntile; ++kt) {
    const int t0 = kt * 32;

    // prefetch next tile (clamped: last iter redundantly reloads, hits L1)
    const int tn = (kt + 1 < ntile) ? (t0 + 32) : t0;
    {
      const __hip_bfloat16* kr0 = kb + (size_t)(tn + pr) * 64;
      const __hip_bfloat16* kr1 = kb + (size_t)(tn + pr + 4) * 64;
      kn[0] = *(const bf16x8*)(kr0 + quad * 8);
      kn[1] = *(const bf16x8*)(kr0 + 32 + quad * 8);
      kn[2] = *(const bf16x8*)(kr1 + quad * 8);
      kn[3] = *(const bf16x8*)(kr1 + 32 + quad * 8);
#pragma unroll
      for (int dt = 0; dt < 4; ++dt)
        vn[dt] = *(const bf16x8*)(vb + (size_t)(dt * 16 + l15) * 2048 + tn + quad * 8);
    }

    // S^T = K * Q^T : c[physrow=quad*4+r][q=l15]; logical key(c0,r) = t0+8*quad+r, c1: +4
    f32x4 c0 = {}, c1 = {};
    c0 = MFMA_BF16(ka[0], bq0, c0);
    c0 = MFMA_BF16(ka[1], bq1, c0);
    c1 = MFMA_BF16(ka[2], bq0, c1);
    c1 = MFMA_BF16(ka[3], bq1, c1);

    // masked scores
    float s0v[4], s1v[4];
#pragma unroll
    for (int r = 0; r < 4; ++r) {
      const int key0 = t0 + 8 * quad + r;
      s0v[r] = (key0     > qi) ? -1e30f : c0[r];
      s1v[r] = (key0 + 4 > qi) ? -1e30f : c1[r];
    }

    // row max: 7 in-register fmax + 2 shfls (lanes sharing l15 differ in bits 4,5)
    float mx = fmaxf(fmaxf(fmaxf(s0v[0], s0v[1]), fmaxf(s0v[2], s0v[3])),
                     fmaxf(fmaxf(s1v[0], s1v[1]), fmaxf(s1v[2], s1v[3])));
    mx = fmaxf(mx, __shfl_xor(mx, 16));
    mx = fmaxf(mx, __shfl_xor(mx, 32));

    const float mnew  = fmaxf(mcur, mx);
    const float alpha = __expf(mcur - mnew);
    mcur = mnew;

    float e0[4], e1[4];
    float rs = 0.f;
#pragma unroll
    for (int r = 0; r < 4; ++r) {
      e0[r] = __expf(s0v[r] - mnew);
      e1[r] = __expf(s1v[r] - mnew);
      rs += e0[r] + e1[r];
    }
    rs += __shfl_xor(rs, 16);
    rs += __shfl_xor(rs, 32);
    lcur = lcur * alpha + rs;

#pragma unroll
    for (int dt = 0; dt < 4; ++dt) {
      o[dt][0] *= alpha; o[dt][1] *= alpha; o[dt][2] *= alpha; o[dt][3] *= alpha;
    }

    // pack P B-operand in-register: P[q=l15][t = t0 + quad*8 + j], j=0..3 <- e0, 4..7 <- e1
    bf16x8 pf;
#pragma unroll
    for (int r = 0; r < 4; ++r) {
      pf[r]     = (short)bf16_bits(e0[r]);
      pf[r + 4] = (short)bf16_bits(e1[r]);
    }

    // O^T[d][q] += V^T * P : A = V^T (lane: d=dt*16+l15... A m-index = l15)
#pragma unroll
    for (int dt = 0; dt < 4; ++dt)
      o[dt] = MFMA_BF16(va[dt], pf, o[dt]);

#pragma unroll
    for (int t = 0; t < 4; ++t) { ka[t] = kn[t]; va[t] = vn[t]; }
  }

  // epilogue: lane holds O[q=qi][d = dt*16 + quad*4 + r]; pack 4 bf16 -> 8B store per dt
  const float inv = 1.0f / lcur;
  const size_t row = ((size_t)(b * 2048 + qi)) * 1024 + h * 64;
#pragma unroll
  for (int dt = 0; dt < 4; ++dt) {
    ushort4 u;
    u.x = bf16_bits(o[dt][0] * inv);
    u.y = bf16_bits(o[dt][1] * inv);
    u.z = bf16_bits(o[dt][2] * inv);
    u.w = bf16_bits(o[dt][3] * inv);
    *(ushort4*)((unsigned short*)ao + row + dt * 16 + quad * 4) = u;
  }
}

extern "C" void kernel_launch(void* const* d_in, const int* in_sizes, int n_in,
                              void* d_out, int out_size, void* d_ws, size_t ws_size,
                              hipStream_t stream)
{
  const float* x    = (const float*)d_in[0];
  // d_in[1] = mask: exactly causal -1e9; applied analytically in attn.
  const float* rf   = (const float*)d_in[2];
  const float* wqkv = (const float*)d_in[3];
  const float* wout = (const float*)d_in[4];
  const float* qw   = (const float*)d_in[5];
  const float* kw   = (const float*)d_in[6];

  const size_t NE = (size_t)2 * 16 * 2048 * 64;   // 4,194,304 elems per [B,H,S,64] tensor
  const int NX    = 2 * 2048 * 1024;              // 4,194,304
  const int NWQKV = 3072 * 1024;                  // 3,145,728
  const int NWOUT = 1024 * 1024;                  // 1,048,576

  __hip_bfloat16* qb  = (__hip_bfloat16*)d_ws;
  __hip_bfloat16* kb  = qb  + NE;
  __hip_bfloat16* vt  = kb  + NE;
  __hip_bfloat16* ao  = vt  + NE;
  __hip_bfloat16* xb  = ao  + NE;
  __hip_bfloat16* wqb = xb  + NX;
  __hip_bfloat16* wob = wqb + NWQKV;
  // total: (4*NE + NX + NWQKV + NWOUT) * 2 B  ~= 48.2 MB

  // f32 -> bf16 conversions
  cvt_f32_bf16<<<NX / 1024,    256, 0, stream>>>(x,    xb,  NX);
  cvt_f32_bf16<<<NWQKV / 1024, 256, 0, stream>>>(wqkv, wqb, NWQKV);
  cvt_f32_bf16<<<NWOUT / 1024, 256, 0, stream>>>(wout, wob, NWOUT);

  // QKV: C[4096,3072] = xb[4096,1024] @ wqb[3072,1024]^T, scatter to q/k/vT
  gemm_bt<0><<<dim3(24, 32), 256, 0, stream>>>(xb, wqb, 1024, qb, kb, vt, nullptr);
  // RMSNorm + RoPE on q,k (131072 rows, 4 waves/block)
  norm_rope<<<32768, 256, 0, stream>>>(qb, kb, rf, qw, kw);
  // causal flash attention -> ao[4096,1024] bf16
  attn<<<dim3(32, 32), 256, 0, stream>>>(qb, kb, vt, ao);
  // out = ao @ wob[1024,1024]^T -> d_out (f32)
  gemm_bt<1><<<dim3(8, 32), 256, 0, stream>>>(ao, wob, 1024,
                                              nullptr, nullptr, nullptr, (float*)d_out);
}